// Round 12
// baseline (554.039 us; speedup 1.0000x reference)
//
#include <hip/hip_runtime.h>
#include <hip/hip_bf16.h>
#include <math.h>

// audio (16,5,256) -> 4 branches x 3 mamba layers -> gates scale x1..x4.
// R12: ZERO inter-block sync. 64 blocks (one per branch,batch) x 1024 threads.
// R10 evidence: agent-scope gbar rounds forced L2 writeback+invalidate (223MB
// ghost writes, 182MB refetch) + 256-block straggle. Now everything is
// in-block __syncthreads. bf16 k8-packed weights (R11), C=4 col-quads with
// in-wave __shfl_xor K-reduction (LDS reads amortized 16 FMA/read; weights
// stay L2-resident per-XCD: branch set 2.7MB < 4MB L2, never invalidated).

#define NTOK 80
#define DM   256
#define DI   512

typedef float f32x4 __attribute__((ext_vector_type(4)));

__device__ __forceinline__ float silu_f(float v) {
    return v / (1.f + expf(-v));
}
__device__ __forceinline__ float dot4v(f32x4 a, f32x4 b) {
    return a.x*b.x + a.y*b.y + a.z*b.z + a.w*b.w;
}
__device__ __forceinline__ unsigned pack2bf(float lo, float hi) {
    unsigned ul = __float_as_uint(lo), uh = __float_as_uint(hi);
    unsigned bl = (ul + 0x7FFFu + ((ul >> 16) & 1u)) >> 16;
    unsigned bh = (uh + 0x7FFFu + ((uh >> 16) & 1u)) >> 16;
    return bl | (bh << 16);
}
__device__ __forceinline__ f32x4 unpk4(unsigned x, unsigned y) {
    f32x4 r;
    r.x = __uint_as_float(x << 16); r.y = __uint_as_float(x & 0xFFFF0000u);
    r.z = __uint_as_float(y << 16); r.w = __uint_as_float(y & 0xFFFF0000u);
    return r;
}

// ---- workspace layout (float indices) ----
#define OFF_SG    0          // 81920
#define OFF_WIN8  81920      // 12 il * [32 k8][1024 c] uint4
#define OFF_WOUT8 1654784    // 12 il * [64 k8][256 c] uint4
#define OFF_GW8   2441216    // 4 i  * [32 k8][256 c] uint4
#define OFF_WXT   2572288    // 12 * [128 k4][48 c] f4 (fp32)

// ---------------- weight repack/convert: 704 blocks x 256 (as R11) ----------
__global__ __launch_bounds__(256) void k_tr(const float* __restrict__ Win,
                                            const float* __restrict__ Wout,
                                            const float* __restrict__ Wx,
                                            const float* __restrict__ gw,
                                            float* __restrict__ ws) {
    __shared__ __align__(16) float SH[8256];
    int b = blockIdx.x, tid = threadIdx.x;

    if (b < 608) {
        const float* src; unsigned* dst; int rowStride, Ctot, c0, k0;
        if (b < 384) {               // Win: 12 il x 16 cb x 2 kh
            int il = b / 32, rest = b % 32, cb = rest >> 1, kh = rest & 1;
            src = Win + (size_t)il * 1024 * 256; rowStride = 256; Ctot = 1024;
            c0 = cb * 64; k0 = kh * 128;
            dst = (unsigned*)(ws + OFF_WIN8) + (size_t)il * 32768 * 4;
        } else if (b < 576) {        // Wout: 12 il x 4 cb x 4 kq
            int t = b - 384; int il = t / 16, rest = t % 16, cb = rest >> 2, kq = rest & 3;
            src = Wout + (size_t)il * 256 * 512; rowStride = 512; Ctot = 256;
            c0 = cb * 64; k0 = kq * 128;
            dst = (unsigned*)(ws + OFF_WOUT8) + (size_t)il * 16384 * 4;
        } else {                     // gw: 4 i x 4 cb x 2 kh
            int t = b - 576; int i = t / 8, rest = t % 8, cb = rest >> 1, kh = rest & 1;
            src = gw + (size_t)i * 256 * 256; rowStride = 256; Ctot = 256;
            c0 = cb * 64; k0 = kh * 128;
            dst = (unsigned*)(ws + OFF_GW8) + (size_t)i * 8192 * 4;
        }
        for (int idx = tid; idx < 64 * 32; idx += 256) {
            int row = idx >> 5, kq4 = idx & 31;
            const float4 v = *(const float4*)(src + (size_t)(c0 + row) * rowStride
                                              + k0 + kq4 * 4);
            float* f = SH + row * 129 + kq4 * 4;
            f[0] = v.x; f[1] = v.y; f[2] = v.z; f[3] = v.w;
        }
        __syncthreads();
        uint4* d4 = (uint4*)dst;
        for (int idx = tid; idx < 1024; idx += 256) {
            int k8l = idx >> 6, c = idx & 63;
            const float* f = SH + c * 129 + k8l * 8;
            uint4 o;
            o.x = pack2bf(f[0], f[1]); o.y = pack2bf(f[2], f[3]);
            o.z = pack2bf(f[4], f[5]); o.w = pack2bf(f[6], f[7]);
            d4[((size_t)(k0 / 8 + k8l)) * Ctot + c0 + c] = o;
        }
    } else {                         // Wx fp32 repack: 96 blocks
        int bb = b - 608; int mat = bb >> 3, tile = bb & 7;
        const float4* src = (const float4*)Wx + (size_t)mat * 6144;
        float4* dst = (float4*)(ws + OFF_WXT) + (size_t)mat * 6144;
        int R = 48, C4 = 128, tilesC = 4;
        int r0 = (tile / tilesC) << 5, cc0 = (tile % tilesC) << 5;
        float4* t4 = (float4*)SH;
        int tx = tid & 31, ty = tid >> 5;
        #pragma unroll
        for (int j = 0; j < 4; ++j) {
            int r = ty + j * 8;
            if (r0 + r < R) t4[r * 33 + tx] = src[(size_t)(r0 + r) * C4 + cc0 + tx];
        }
        __syncthreads();
        #pragma unroll
        for (int j = 0; j < 4; ++j) {
            int cc = ty + j * 8;
            if (r0 + tx < R) dst[(size_t)(cc0 + cc) * R + r0 + tx] = t4[tx * 33 + cc];
        }
    }
}

// ---------------- fused chain: 64 blocks x 1024 threads, no inter-block sync --
__global__ __launch_bounds__(1024, 4) void k_chain1k(
    const float* __restrict__ audio,
    const float* __restrict__ ln_g, const float* __restrict__ ln_b,
    const float* __restrict__ Wc,   const float* __restrict__ bc,
    const float* __restrict__ Wdt,  const float* __restrict__ bdt,
    const float* __restrict__ Alog, const float* __restrict__ Dp,
    const float* __restrict__ gb,   float* __restrict__ ws)
{
    int blk = blockIdx.x;
    int i = blk & 3, b = blk >> 2;   // XCD = blk%8 in {i, i+4}: branch/XCD L2 locality
    int tid = threadIdx.x, lane = tid & 63, wv = tid >> 6;

    float* s_g = ws + OFF_SG;

    __shared__ __align__(16) float a_l  [1280];   // activations (5x256)
    __shared__ __align__(16) float aln_l[1280];   // LN out (residual base)
    __shared__ __align__(16) float xz_l [5120];   // in_proj out [5][1024]; reused as partials
    __shared__ __align__(16) float xc_l [2560];   // conv+silu [5][512]
    __shared__ __align__(16) float y_l  [2560];   // scan out [5][512]
    __shared__ __align__(16) float dbl_l[240];
    __shared__ __align__(16) float xp_l [960];

    if (tid < 320)
        ((f32x4*)a_l)[tid] = ((const f32x4*)(audio + (size_t)b * 1280))[tid];
    __syncthreads();

    for (int l = 0; l < 3; ++l) {
        int il = i * 3 + l;

        // ---- LayerNorm: waves 0..4 handle rows 0..4 ----
        if (wv < 5) {
            f32x4 x = ((f32x4*)a_l)[wv*64 + lane];
            float s = x.x + x.y + x.z + x.w;
            #pragma unroll
            for (int o = 32; o > 0; o >>= 1) s += __shfl_down(s, o, 64);
            float mu = __shfl(s, 0, 64) * (1.f/256.f);
            f32x4 d = x - mu;
            float v2 = d.x*d.x + d.y*d.y + d.z*d.z + d.w*d.w;
            #pragma unroll
            for (int o = 32; o > 0; o >>= 1) v2 += __shfl_down(v2, o, 64);
            float rstd = rsqrtf(__shfl(v2, 0, 64) * (1.f/256.f) + 1e-5f);
            f32x4 g4 = ((const f32x4*)(ln_g + (size_t)il*DM))[lane];
            f32x4 b4 = ((const f32x4*)(ln_b + (size_t)il*DM))[lane];
            ((f32x4*)aln_l)[wv*64 + lane] = d * rstd * g4 + b4;
        }
        __syncthreads();

        // ---- in_proj: wave -> 64 cols (16 quads), kq in lanes (shfl-reduced) --
        {
            int cq = lane & 15, kq = lane >> 4;
            int col0 = wv * 64 + cq * 4;
            const uint4* W8 = (const uint4*)(ws + OFF_WIN8) + (size_t)il * 32768;
            const f32x4* a4 = (const f32x4*)aln_l;   // [5][64]
            float acc[5][4];
            #pragma unroll
            for (int r = 0; r < 5; ++r)
                #pragma unroll
                for (int j = 0; j < 4; ++j) acc[r][j] = 0.f;
            #pragma unroll
            for (int t8 = 0; t8 < 8; ++t8) {
                int k8 = kq * 8 + t8;
                f32x4 wl[4], wh[4];
                #pragma unroll
                for (int j = 0; j < 4; ++j) {
                    uint4 w = W8[(size_t)k8 * 1024 + col0 + j];
                    wl[j] = unpk4(w.x, w.y); wh[j] = unpk4(w.z, w.w);
                }
                #pragma unroll
                for (int r = 0; r < 5; ++r) {
                    f32x4 x0 = a4[r*64 + k8*2], x1 = a4[r*64 + k8*2 + 1];
                    #pragma unroll
                    for (int j = 0; j < 4; ++j)
                        acc[r][j] += dot4v(wl[j], x0) + dot4v(wh[j], x1);
                }
            }
            #pragma unroll
            for (int r = 0; r < 5; ++r)
                #pragma unroll
                for (int j = 0; j < 4; ++j) {
                    float v = acc[r][j];
                    v += __shfl_xor(v, 16, 64);
                    v += __shfl_xor(v, 32, 64);
                    acc[r][j] = v;
                }
            if (kq == 0) {
                #pragma unroll
                for (int r = 0; r < 5; ++r) {
                    f32x4 o = {acc[r][0], acc[r][1], acc[r][2], acc[r][3]};
                    ((f32x4*)xz_l)[r*256 + (col0 >> 2)] = o;
                }
            }
        }
        __syncthreads();

        // ---- depthwise causal conv (k=4) + bias + SiLU: cols 0..511 ----
        for (int v = tid; v < 2560; v += 1024) {
            int r = v >> 9, dl = v & 511;
            const float* wr = Wc + ((size_t)il*DI + dl)*4;
            float acc = bc[(size_t)il*DI + dl] + wr[3]*xz_l[r*1024 + dl];
            if (r >= 1) acc += wr[2]*xz_l[(r-1)*1024 + dl];
            if (r >= 2) acc += wr[1]*xz_l[(r-2)*1024 + dl];
            if (r >= 3) acc += wr[0]*xz_l[(r-3)*1024 + dl];
            xc_l[r*512 + dl] = silu_f(acc);
        }
        __syncthreads();

        // ---- x_proj: 48 cols x 5 rows, K=512 split 4 (fp32) ----
        if (tid < 960) {
            int c = tid % 48, r = (tid / 48) % 5, kh = tid / 240;
            const f32x4* wp = (const f32x4*)(ws + OFF_WXT) + (size_t)il*6144 + c;
            const f32x4* x4 = (const f32x4*)xc_l + r*128 + kh*32;
            float acc = 0.f;
            #pragma unroll
            for (int kk = 0; kk < 32; ++kk)
                acc += dot4v(wp[(size_t)(kh*32 + kk)*48], x4[kk]);
            xp_l[tid] = acc;
        }
        __syncthreads();
        if (tid < 240)
            dbl_l[tid] = xp_l[tid] + xp_l[240+tid] + xp_l[480+tid] + xp_l[720+tid];
        __syncthreads();

        // ---- scan (dt-proj fused) + D skip + z gate: 512 channels ----
        if (tid < 512) {
            int d = tid;
            float A[16], h[16];
            const f32x4* al4 = (const f32x4*)(Alog + ((size_t)il*DI + d)*16);
            f32x4 av0 = al4[0], av1 = al4[1], av2 = al4[2], av3 = al4[3];
            A[0]=-expf(av0.x); A[1]=-expf(av0.y); A[2]=-expf(av0.z); A[3]=-expf(av0.w);
            A[4]=-expf(av1.x); A[5]=-expf(av1.y); A[6]=-expf(av1.z); A[7]=-expf(av1.w);
            A[8]=-expf(av2.x); A[9]=-expf(av2.y); A[10]=-expf(av2.z); A[11]=-expf(av2.w);
            A[12]=-expf(av3.x); A[13]=-expf(av3.y); A[14]=-expf(av3.z); A[15]=-expf(av3.w);
            #pragma unroll
            for (int n = 0; n < 16; ++n) h[n] = 0.f;
            const f32x4* wd4 = (const f32x4*)(Wdt + ((size_t)il*DI + d)*16);
            f32x4 w0 = wd4[0], w1 = wd4[1], w2 = wd4[2], w3 = wd4[3];
            float bdtv = bdt[(size_t)il*DI + d];
            float dv   = Dp[(size_t)il*DI + d];
            #pragma unroll
            for (int t = 0; t < 5; ++t) {
                const float* db = dbl_l + t*48;
                float acc = bdtv;
                acc += db[0]*w0.x + db[1]*w0.y + db[2]*w0.z + db[3]*w0.w;
                acc += db[4]*w1.x + db[5]*w1.y + db[6]*w1.z + db[7]*w1.w;
                acc += db[8]*w2.x + db[9]*w2.y + db[10]*w2.z + db[11]*w2.w;
                acc += db[12]*w3.x + db[13]*w3.y + db[14]*w3.z + db[15]*w3.w;
                float dtv = fmaxf(acc, 0.f) + log1pf(expf(-fabsf(acc)));
                float xv  = xc_l[t*512 + d];
                float zv  = xz_l[t*1024 + 512 + d];
                float dx  = dtv * xv;
                float yacc = 0.f;
                #pragma unroll
                for (int n = 0; n < 16; ++n) {
                    h[n] = expf(dtv*A[n])*h[n] + dx*db[16 + n];
                    yacc += h[n]*db[32 + n];
                }
                y_l[t*512 + d] = (yacc + xv*dv) * silu_f(zv);
            }
        }
        __syncthreads();   // xz_l now free -> reuse as out_proj partials

        // ---- out_proj: 64 quads x 16 K-splits (4 in-lane + 4 groups) ----
        {
            int cq = lane & 15, kqi = lane >> 4;
            int qg = (wv & 3) * 16 + cq;      // quad 0..63
            int kg = wv >> 2;                 // K group 0..3
            int kq = kg * 4 + kqi;            // 0..15, K=32 each (4 k8)
            int col0 = qg * 4;
            const uint4* W8 = (const uint4*)(ws + OFF_WOUT8) + (size_t)il * 16384;
            const f32x4* y4 = (const f32x4*)y_l;   // [5][128]
            float acc[5][4];
            #pragma unroll
            for (int r = 0; r < 5; ++r)
                #pragma unroll
                for (int j = 0; j < 4; ++j) acc[r][j] = 0.f;
            #pragma unroll
            for (int t8 = 0; t8 < 4; ++t8) {
                int k8 = kq * 4 + t8;
                f32x4 wl[4], wh[4];
                #pragma unroll
                for (int j = 0; j < 4; ++j) {
                    uint4 w = W8[(size_t)k8 * 256 + col0 + j];
                    wl[j] = unpk4(w.x, w.y); wh[j] = unpk4(w.z, w.w);
                }
                #pragma unroll
                for (int r = 0; r < 5; ++r) {
                    f32x4 x0 = y4[r*128 + k8*2], x1 = y4[r*128 + k8*2 + 1];
                    #pragma unroll
                    for (int j = 0; j < 4; ++j)
                        acc[r][j] += dot4v(wl[j], x0) + dot4v(wh[j], x1);
                }
            }
            #pragma unroll
            for (int r = 0; r < 5; ++r)
                #pragma unroll
                for (int j = 0; j < 4; ++j) {
                    float v = acc[r][j];
                    v += __shfl_xor(v, 16, 64);
                    v += __shfl_xor(v, 32, 64);
                    acc[r][j] = v;
                }
            if (kqi == 0) {
                #pragma unroll
                for (int r = 0; r < 5; ++r) {
                    f32x4 o = {acc[r][0], acc[r][1], acc[r][2], acc[r][3]};
                    ((f32x4*)xz_l)[kg*320 + r*64 + qg] = o;
                }
            }
        }
        __syncthreads();
        // reduce 4 K-groups + residual
        for (int v = tid; v < 1280; v += 1024)
            a_l[v] = aln_l[v] + xz_l[v] + xz_l[1280+v] + xz_l[2560+v] + xz_l[3840+v];
        __syncthreads();
    }

    // ---- gates: 64 quads x 16 K-splits (K=16 each = 2 k8), permuted store ----
    {
        int cq = lane & 15, kqi = lane >> 4;
        int qg = (wv & 3) * 16 + cq;
        int kg = wv >> 2;
        int kq = kg * 4 + kqi;
        int col0 = qg * 4;
        const uint4* G8 = (const uint4*)(ws + OFF_GW8) + (size_t)i * 8192;
        const f32x4* a4 = (const f32x4*)a_l;   // [5][64]
        float acc[5][4];
        #pragma unroll
        for (int r = 0; r < 5; ++r)
            #pragma unroll
            for (int j = 0; j < 4; ++j) acc[r][j] = 0.f;
        #pragma unroll
        for (int t8 = 0; t8 < 2; ++t8) {
            int k8 = kq * 2 + t8;
            f32x4 wl[4], wh[4];
            #pragma unroll
            for (int j = 0; j < 4; ++j) {
                uint4 w = G8[(size_t)k8 * 256 + col0 + j];
                wl[j] = unpk4(w.x, w.y); wh[j] = unpk4(w.z, w.w);
            }
            #pragma unroll
            for (int r = 0; r < 5; ++r) {
                f32x4 x0 = a4[r*64 + k8*2], x1 = a4[r*64 + k8*2 + 1];
                #pragma unroll
                for (int j = 0; j < 4; ++j)
                    acc[r][j] += dot4v(wl[j], x0) + dot4v(wh[j], x1);
            }
        }
        #pragma unroll
        for (int r = 0; r < 5; ++r)
            #pragma unroll
            for (int j = 0; j < 4; ++j) {
                float v = acc[r][j];
                v += __shfl_xor(v, 16, 64);
                v += __shfl_xor(v, 32, 64);
                acc[r][j] = v;
            }
        if (kqi == 0) {
            #pragma unroll
            for (int r = 0; r < 5; ++r) {
                f32x4 o = {acc[r][0], acc[r][1], acc[r][2], acc[r][3]};
                ((f32x4*)xz_l)[kg*320 + r*64 + qg] = o;
            }
        }
    }
    __syncthreads();
    for (int v = tid; v < 1280; v += 1024) {
        int r = v >> 8, c = v & 255;
        float val = gb[(size_t)i*DM + c]
                  + xz_l[v] + xz_l[1280+v] + xz_l[2560+v] + xz_l[3840+v];
        int row = b*5 + r;
        int np  = (i == 0) ? row : (r*16 + b);
        s_g[((size_t)i*NTOK + np)*DM + c] = 1.f + silu_f(val);
    }
}

// ---------------- fused elementwise: o = x * s[plane], nontemporal ----------
__global__ __launch_bounds__(256) void k_elem(
    const float* __restrict__ x1, const float* __restrict__ x2,
    const float* __restrict__ x3, const float* __restrict__ x4,
    const float* __restrict__ audio, const float* __restrict__ s_g,
    float* __restrict__ out) {
    int b = blockIdx.x;
    int t = threadIdx.x;

    if (b < 512) {
        const float* s = s_g + 3 * NTOK * DM;
        const f32x4* xv = (const f32x4*)x4;
        f32x4* ov = (f32x4*)out;
        const int total4 = 1003520 / 4;
        for (int v = b * 256 + t; v < total4; v += 512 * 256) {
            f32x4 x = __builtin_nontemporal_load(&xv[v]);
#pragma unroll
            for (int j = 0; j < 4; ++j) {
                int idx = v * 4 + j;
                x[j] *= s[idx / 49];
            }
            __builtin_nontemporal_store(x, &ov[v]);
        }
    } else if (b < 1024) {
        const float* s = s_g + 2 * NTOK * DM;
        const f32x4* xv = (const f32x4*)x3;
        f32x4* ov = (f32x4*)(out + 1003520);
        const int total4 = 4014080 / 4;
        for (int v = (b - 512) * 256 + t; v < total4; v += 512 * 256) {
            float f = s[v / 49];
            f32x4 x = __builtin_nontemporal_load(&xv[v]);
            x *= f;
            __builtin_nontemporal_store(x, &ov[v]);
        }
    } else if (b < 2048) {
        const float* s = s_g + 1 * NTOK * DM;
        const f32x4* xv = (const f32x4*)x2;
        f32x4* ov = (f32x4*)(out + 5017600);
        const int total4 = 16056320 / 4;
        for (int v = (b - 1024) * 256 + t; v < total4; v += 1024 * 256) {
            float f = s[v / 196];
            f32x4 x = __builtin_nontemporal_load(&xv[v]);
            x *= f;
            __builtin_nontemporal_store(x, &ov[v]);
        }
    } else if (b < 6144) {
        const float* s = s_g;
        const f32x4* xv = (const f32x4*)x1;
        f32x4* ov = (f32x4*)(out + 21073920);
        const int total4 = 64225280 / 4;
        for (int v = (b - 2048) * 256 + t; v < total4; v += 4096 * 256) {
            float f = s[v / 784];
            f32x4 x = __builtin_nontemporal_load(&xv[v]);
            x *= f;
            __builtin_nontemporal_store(x, &ov[v]);
        }
    } else {
        int idx = (b - 6144) * 256 + t;
        out[85299200 + idx] = audio[idx];
    }
}

extern "C" void kernel_launch(void* const* d_in, const int* in_sizes, int n_in,
                              void* d_out, int out_size, void* d_ws, size_t ws_size,
                              hipStream_t stream) {
    const float* x1        = (const float*)d_in[0];
    const float* x2        = (const float*)d_in[1];
    const float* x3        = (const float*)d_in[2];
    const float* x4        = (const float*)d_in[3];
    const float* audio     = (const float*)d_in[4];
    const float* ln_g      = (const float*)d_in[5];
    const float* ln_b      = (const float*)d_in[6];
    const float* in_proj_w = (const float*)d_in[7];
    const float* conv_w    = (const float*)d_in[8];
    const float* conv_b    = (const float*)d_in[9];
    const float* xproj_w   = (const float*)d_in[10];
    const float* dt_w      = (const float*)d_in[11];
    const float* dt_b      = (const float*)d_in[12];
    const float* A_log     = (const float*)d_in[13];
    const float* Dvec      = (const float*)d_in[14];
    const float* out_proj_w= (const float*)d_in[15];
    const float* gate_w    = (const float*)d_in[16];
    const float* gate_b    = (const float*)d_in[17];

    float* ws = (float*)d_ws;

    k_tr<<<704, 256, 0, stream>>>(in_proj_w, out_proj_w, xproj_w, gate_w, ws);
    k_chain1k<<<64, 1024, 0, stream>>>(audio, ln_g, ln_b, conv_w, conv_b,
                                       dt_w, dt_b, A_log, Dvec, gate_b, ws);
    k_elem<<<6224, 256, 0, stream>>>(x1, x2, x3, x4, audio, ws + OFF_SG,
                                     (float*)d_out);
}

// Round 13
// 230.604 us; speedup vs baseline: 2.4026x; 2.4026x over previous
//
#include <hip/hip_runtime.h>
#include <hip/hip_bf16.h>
#include <math.h>

// audio (16,5,256) -> 4 branches x 3 mamba layers -> gates scale x1..x4.
// R13 = R11 (best, 239us: 64 groups x 4 members, bf16 k8 weights, C=2 pairs)
// with the agent-scope ACQUIRE removed from the group barrier. Acquire emits
// buffer_inv (whole-XCD L2 invalidate) -> weights evicted 6x/call (R10: 182MB
// refetch). Now: producer RELEASE (wbl2 writeback only), consumer RELAXED
// poll + sc1 read-through atomic loads on just the exchanged data.

#define NTOK 80
#define DM   256
#define DI   512

typedef float f32x4 __attribute__((ext_vector_type(4)));

__device__ __forceinline__ float silu_f(float v) {
    return v / (1.f + expf(-v));
}
__device__ __forceinline__ float dot4v(f32x4 a, f32x4 b) {
    return a.x*b.x + a.y*b.y + a.z*b.z + a.w*b.w;
}
__device__ __forceinline__ unsigned pack2bf(float lo, float hi) {
    unsigned ul = __float_as_uint(lo), uh = __float_as_uint(hi);
    unsigned bl = (ul + 0x7FFFu + ((ul >> 16) & 1u)) >> 16;
    unsigned bh = (uh + 0x7FFFu + ((uh >> 16) & 1u)) >> 16;
    return bl | (bh << 16);
}
__device__ __forceinline__ f32x4 unpk4(unsigned x, unsigned y) {
    f32x4 r;
    r.x = __uint_as_float(x << 16); r.y = __uint_as_float(x & 0xFFFF0000u);
    r.z = __uint_as_float(y << 16); r.w = __uint_as_float(y & 0xFFFF0000u);
    return r;
}
// read-through load (sc1) of cross-block data; no cache-wide invalidate
__device__ __forceinline__ float gload(const float* p) {
    return __hip_atomic_load((float*)p, __ATOMIC_RELAXED, __HIP_MEMORY_SCOPE_AGENT);
}

// ---- workspace layout (float indices) ----
#define OFF_SG    0          // 81920
#define OFF_WIN8  81920      // 12 il * [32 k8][1024 c] uint4
#define OFF_WOUT8 1654784    // 12 il * [64 k8][256 c] uint4
#define OFF_GW8   2441216    // 4 i  * [32 k8][256 c] uint4
#define OFF_WXT   2572288    // 12 * [128 k4][48 c] f4 (fp32)
#define OFF_DBLP  2867200    // 64 groups * 4 q * 240
#define OFF_OUTP  2928640    // 64 groups * 4 q * 1280
#define OFF_BAR   3256320    // 1024 uints

// ---------------- weight repack/convert: 704 blocks x 256 ----------------
__global__ __launch_bounds__(256) void k_tr(const float* __restrict__ Win,
                                            const float* __restrict__ Wout,
                                            const float* __restrict__ Wx,
                                            const float* __restrict__ gw,
                                            float* __restrict__ ws) {
    __shared__ __align__(16) float SH[8256];
    int b = blockIdx.x, tid = threadIdx.x;
    if (b == 0) {
        unsigned* barp = (unsigned*)(ws + OFF_BAR);
        #pragma unroll
        for (int j = 0; j < 4; ++j) barp[j * 256 + tid] = 0u;
    }

    if (b < 608) {
        const float* src; unsigned* dst; int rowStride, Ctot, c0, k0;
        if (b < 384) {               // Win
            int il = b / 32, rest = b % 32, cb = rest >> 1, kh = rest & 1;
            src = Win + (size_t)il * 1024 * 256; rowStride = 256; Ctot = 1024;
            c0 = cb * 64; k0 = kh * 128;
            dst = (unsigned*)(ws + OFF_WIN8) + (size_t)il * 32768 * 4;
        } else if (b < 576) {        // Wout
            int t = b - 384; int il = t / 16, rest = t % 16, cb = rest >> 2, kq = rest & 3;
            src = Wout + (size_t)il * 256 * 512; rowStride = 512; Ctot = 256;
            c0 = cb * 64; k0 = kq * 128;
            dst = (unsigned*)(ws + OFF_WOUT8) + (size_t)il * 16384 * 4;
        } else {                     // gw
            int t = b - 576; int i = t / 8, rest = t % 8, cb = rest >> 1, kh = rest & 1;
            src = gw + (size_t)i * 256 * 256; rowStride = 256; Ctot = 256;
            c0 = cb * 64; k0 = kh * 128;
            dst = (unsigned*)(ws + OFF_GW8) + (size_t)i * 8192 * 4;
        }
        for (int idx = tid; idx < 64 * 32; idx += 256) {
            int row = idx >> 5, kq4 = idx & 31;
            const float4 v = *(const float4*)(src + (size_t)(c0 + row) * rowStride
                                              + k0 + kq4 * 4);
            float* f = SH + row * 129 + kq4 * 4;
            f[0] = v.x; f[1] = v.y; f[2] = v.z; f[3] = v.w;
        }
        __syncthreads();
        uint4* d4 = (uint4*)dst;
        for (int idx = tid; idx < 1024; idx += 256) {
            int k8l = idx >> 6, c = idx & 63;
            const float* f = SH + c * 129 + k8l * 8;
            uint4 o;
            o.x = pack2bf(f[0], f[1]); o.y = pack2bf(f[2], f[3]);
            o.z = pack2bf(f[4], f[5]); o.w = pack2bf(f[6], f[7]);
            d4[((size_t)(k0 / 8 + k8l)) * Ctot + c0 + c] = o;
        }
    } else {                         // Wx fp32 repack
        int bb = b - 608; int mat = bb >> 3, tile = bb & 7;
        const float4* src = (const float4*)Wx + (size_t)mat * 6144;
        float4* dst = (float4*)(ws + OFF_WXT) + (size_t)mat * 6144;
        int R = 48, C4 = 128, tilesC = 4;
        int r0 = (tile / tilesC) << 5, cc0 = (tile % tilesC) << 5;
        float4* t4 = (float4*)SH;
        int tx = tid & 31, ty = tid >> 5;
        #pragma unroll
        for (int j = 0; j < 4; ++j) {
            int r = ty + j * 8;
            if (r0 + r < R) t4[r * 33 + tx] = src[(size_t)(r0 + r) * C4 + cc0 + tx];
        }
        __syncthreads();
        #pragma unroll
        for (int j = 0; j < 4; ++j) {
            int cc = ty + j * 8;
            if (r0 + tx < R) dst[(size_t)(cc0 + cc) * R + r0 + tx] = t4[tx * 33 + cc];
        }
    }
}

// 4-member barrier WITHOUT acquire-invalidate: RELEASE add (wbl2 writeback
// keeps L2 weight lines) + RELAXED poll. Consumers use sc1 gload() on data.
__device__ __forceinline__ void gbar(unsigned* slot) {
    __syncthreads();   // compiler emits s_waitcnt vmcnt(0) before s_barrier
    if (threadIdx.x == 0) {
        __hip_atomic_fetch_add(slot, 1u, __ATOMIC_RELEASE, __HIP_MEMORY_SCOPE_AGENT);
        while (__hip_atomic_load(slot, __ATOMIC_RELAXED, __HIP_MEMORY_SCOPE_AGENT) < 4u)
            __builtin_amdgcn_s_sleep(1);
    }
    __syncthreads();
}

// ---------------- split mamba chain + gates: 256 blocks x 512 threads ----------
__global__ __launch_bounds__(512) void k_chain4b(
    const float* __restrict__ audio,
    const float* __restrict__ ln_g, const float* __restrict__ ln_b,
    const float* __restrict__ Wc,   const float* __restrict__ bc,
    const float* __restrict__ Wdt,  const float* __restrict__ bdt,
    const float* __restrict__ Alog, const float* __restrict__ Dp,
    const float* __restrict__ gb,   float* __restrict__ ws)
{
    int gid = blockIdx.x & 63;    // group = (branch,batch); members co-XCD
    int q   = blockIdx.x >> 6;    // member 0..3
    int i = gid & 3, b = gid >> 2;
    int tid = threadIdx.x, lane = tid & 63, wave = tid >> 6;
    int dq = q * 128;

    float* s_g  = ws + OFF_SG;
    float* dblp = ws + OFF_DBLP + (size_t)gid * 4 * 240;
    float* outp = ws + OFF_OUTP + (size_t)gid * 4 * 1280;
    unsigned* bar = (unsigned*)(ws + OFF_BAR) + gid * 16;

    __shared__ __align__(16) float a_l   [1280];
    __shared__ __align__(16) float aln_l [1280];
    __shared__ __align__(16) float xz_l  [1280];  // [r][0..127]=xc-pre, [128..255]=z
    __shared__ __align__(16) float xc_l  [640];
    __shared__ __align__(16) float y_l   [640];
    __shared__ __align__(16) float dbl_l [240];
    __shared__ __align__(16) float xp_l  [480];
    __shared__ __align__(16) float part_l[5120];

    if (tid < 320)
        ((f32x4*)a_l)[tid] = ((const f32x4*)(audio + (size_t)b * 1280))[tid];
    __syncthreads();

    for (int l = 0; l < 3; ++l) {
        int il = i * 3 + l;

        // ---- LayerNorm (redundant per member) ----
        if (wave < 5) {
            f32x4 x = ((f32x4*)a_l)[wave*64 + lane];
            float s = x.x + x.y + x.z + x.w;
            #pragma unroll
            for (int o = 32; o > 0; o >>= 1) s += __shfl_down(s, o, 64);
            float mu = __shfl(s, 0, 64) * (1.f/256.f);
            f32x4 d = x - mu;
            float v2 = d.x*d.x + d.y*d.y + d.z*d.z + d.w*d.w;
            #pragma unroll
            for (int o = 32; o > 0; o >>= 1) v2 += __shfl_down(v2, o, 64);
            float rstd = rsqrtf(__shfl(v2, 0, 64) * (1.f/256.f) + 1e-5f);
            f32x4 g4 = ((const f32x4*)(ln_g + (size_t)il*DM))[lane];
            f32x4 b4 = ((const f32x4*)(ln_b + (size_t)il*DM))[lane];
            ((f32x4*)aln_l)[wave*64 + lane] = d * rstd * g4 + b4;
        }
        __syncthreads();

        // ---- in_proj: own 256 cols as 128 pairs, C=2, K split 4 (kq) ----
        {
            int cp = tid & 127, kq = tid >> 7;
            int lc = 2*cp;
            int cA = (cp < 64) ? (dq + 2*cp) : (512 + dq + 2*(cp-64));
            const uint4* W8 = (const uint4*)(ws + OFF_WIN8) + (size_t)il * 32768;
            const f32x4* a4 = (const f32x4*)aln_l;   // [5][64]
            float accA[5] = {0,0,0,0,0}, accB[5] = {0,0,0,0,0};
            #pragma unroll
            for (int j = 0; j < 8; ++j) {
                int k8 = kq*8 + j;
                uint4 wa = W8[(size_t)k8*1024 + cA];
                uint4 wb = W8[(size_t)k8*1024 + cA + 1];
                f32x4 wa0 = unpk4(wa.x, wa.y), wa1 = unpk4(wa.z, wa.w);
                f32x4 wb0 = unpk4(wb.x, wb.y), wb1 = unpk4(wb.z, wb.w);
                #pragma unroll
                for (int r = 0; r < 5; ++r) {
                    f32x4 a0 = a4[r*64 + k8*2], a1 = a4[r*64 + k8*2 + 1];
                    accA[r] += dot4v(wa0, a0) + dot4v(wa1, a1);
                    accB[r] += dot4v(wb0, a0) + dot4v(wb1, a1);
                }
            }
            #pragma unroll
            for (int r = 0; r < 5; ++r) {
                part_l[kq*1280 + r*256 + lc]     = accA[r];
                part_l[kq*1280 + r*256 + lc + 1] = accB[r];
            }
        }
        __syncthreads();
        for (int v = tid; v < 1280; v += 512)
            xz_l[v] = part_l[v] + part_l[1280+v] + part_l[2560+v] + part_l[3840+v];
        __syncthreads();

        // ---- depthwise causal conv (k=4) + bias + SiLU on own 128 ch ----
        for (int v = tid; v < 640; v += 512) {
            int r = v >> 7, dl = v & 127;
            int ch = dq + dl;
            const float* wr = Wc + ((size_t)il*DI + ch)*4;
            float acc = bc[(size_t)il*DI + ch] + wr[3]*xz_l[r*256 + dl];
            if (r >= 1) acc += wr[2]*xz_l[(r-1)*256 + dl];
            if (r >= 2) acc += wr[1]*xz_l[(r-2)*256 + dl];
            if (r >= 3) acc += wr[0]*xz_l[(r-3)*256 + dl];
            xc_l[r*128 + dl] = silu_f(acc);
        }
        __syncthreads();

        // ---- x_proj partial over own K=128 (fp32) ----
        if (tid < 480) {
            int c = tid % 48, r = (tid / 48) % 5, kh = tid / 240;
            const f32x4* wp = (const f32x4*)(ws + OFF_WXT) + (size_t)il*6144 + c;
            const f32x4* x4 = (const f32x4*)xc_l + r*32 + kh*16;
            float acc = 0.f;
            #pragma unroll
            for (int kk = 0; kk < 16; ++kk)
                acc += dot4v(wp[(size_t)(q*32 + kh*16 + kk)*48], x4[kk]);
            xp_l[tid] = acc;
        }
        __syncthreads();
        if (tid < 240) dblp[q*240 + tid] = xp_l[tid] + xp_l[240 + tid];
        gbar(bar + 2*l);
        if (tid < 240)
            dbl_l[tid] = gload(dblp + tid) + gload(dblp + 240 + tid)
                       + gload(dblp + 480 + tid) + gload(dblp + 720 + tid);
        __syncthreads();

        // ---- scan (dt-proj fused) + D skip + z gate on own 128 ch ----
        if (tid < 128) {
            int d = dq + tid;
            float A[16], h[16];
            const f32x4* al4 = (const f32x4*)(Alog + ((size_t)il*DI + d)*16);
            f32x4 av0 = al4[0], av1 = al4[1], av2 = al4[2], av3 = al4[3];
            A[0]=-expf(av0.x); A[1]=-expf(av0.y); A[2]=-expf(av0.z); A[3]=-expf(av0.w);
            A[4]=-expf(av1.x); A[5]=-expf(av1.y); A[6]=-expf(av1.z); A[7]=-expf(av1.w);
            A[8]=-expf(av2.x); A[9]=-expf(av2.y); A[10]=-expf(av2.z); A[11]=-expf(av2.w);
            A[12]=-expf(av3.x); A[13]=-expf(av3.y); A[14]=-expf(av3.z); A[15]=-expf(av3.w);
            #pragma unroll
            for (int n = 0; n < 16; ++n) h[n] = 0.f;
            const f32x4* wd4 = (const f32x4*)(Wdt + ((size_t)il*DI + d)*16);
            f32x4 w0 = wd4[0], w1 = wd4[1], w2 = wd4[2], w3 = wd4[3];
            float bdtv = bdt[(size_t)il*DI + d];
            float dv   = Dp[(size_t)il*DI + d];
            #pragma unroll
            for (int t = 0; t < 5; ++t) {
                const float* db = dbl_l + t*48;
                float acc = bdtv;
                acc += db[0]*w0.x + db[1]*w0.y + db[2]*w0.z + db[3]*w0.w;
                acc += db[4]*w1.x + db[5]*w1.y + db[6]*w1.z + db[7]*w1.w;
                acc += db[8]*w2.x + db[9]*w2.y + db[10]*w2.z + db[11]*w2.w;
                acc += db[12]*w3.x + db[13]*w3.y + db[14]*w3.z + db[15]*w3.w;
                float dtv = fmaxf(acc, 0.f) + log1pf(expf(-fabsf(acc)));
                float xv  = xc_l[t*128 + tid];
                float zv  = xz_l[t*256 + 128 + tid];
                float dx  = dtv * xv;
                float yacc = 0.f;
                #pragma unroll
                for (int n = 0; n < 16; ++n) {
                    h[n] = expf(dtv*A[n])*h[n] + dx*db[16 + n];
                    yacc += h[n]*db[32 + n];
                }
                y_l[t*128 + tid] = (yacc + xv*dv) * silu_f(zv);
            }
        }
        __syncthreads();

        // ---- out_proj partial: 256 cols as 128 pairs, own K=128, split 4 ----
        {
            int cp = tid & 127, kq = tid >> 7;
            int cA = 2*cp;
            const uint4* W8 = (const uint4*)(ws + OFF_WOUT8) + (size_t)il * 16384;
            const f32x4* y4 = (const f32x4*)y_l;   // [5][32]
            float accA[5] = {0,0,0,0,0}, accB[5] = {0,0,0,0,0};
            #pragma unroll
            for (int j = 0; j < 4; ++j) {
                int k8l = kq*4 + j;
                int k8g = q*16 + k8l;
                uint4 wa = W8[(size_t)k8g*256 + cA];
                uint4 wb = W8[(size_t)k8g*256 + cA + 1];
                f32x4 wa0 = unpk4(wa.x, wa.y), wa1 = unpk4(wa.z, wa.w);
                f32x4 wb0 = unpk4(wb.x, wb.y), wb1 = unpk4(wb.z, wb.w);
                #pragma unroll
                for (int r = 0; r < 5; ++r) {
                    f32x4 y0 = y4[r*32 + k8l*2], y1 = y4[r*32 + k8l*2 + 1];
                    accA[r] += dot4v(wa0, y0) + dot4v(wa1, y1);
                    accB[r] += dot4v(wb0, y0) + dot4v(wb1, y1);
                }
            }
            #pragma unroll
            for (int r = 0; r < 5; ++r) {
                part_l[kq*1280 + r*256 + cA]     = accA[r];
                part_l[kq*1280 + r*256 + cA + 1] = accB[r];
            }
        }
        __syncthreads();
        for (int v = tid; v < 1280; v += 512)
            outp[q*1280 + v] = part_l[v] + part_l[1280+v] + part_l[2560+v] + part_l[3840+v];
        gbar(bar + 2*l + 1);
        for (int v = tid; v < 1280; v += 512)
            a_l[v] = aln_l[v] + gload(outp + v) + gload(outp + 1280 + v)
                   + gload(outp + 2560 + v) + gload(outp + 3840 + v);
        __syncthreads();
    }

    // ---- gates: own 64 cols as 32 pairs, K=256 split 16 (kq) ----
    {
        int cp = tid & 31, kq = tid >> 5;
        int gA = q*64 + 2*cp;
        const uint4* G8 = (const uint4*)(ws + OFF_GW8) + (size_t)i * 8192;
        const f32x4* a4 = (const f32x4*)a_l;   // [5][64]
        float accA[5] = {0,0,0,0,0}, accB[5] = {0,0,0,0,0};
        #pragma unroll
        for (int j = 0; j < 2; ++j) {
            int k8 = kq*2 + j;
            uint4 wa = G8[(size_t)k8*256 + gA];
            uint4 wb = G8[(size_t)k8*256 + gA + 1];
            f32x4 wa0 = unpk4(wa.x, wa.y), wa1 = unpk4(wa.z, wa.w);
            f32x4 wb0 = unpk4(wb.x, wb.y), wb1 = unpk4(wb.z, wb.w);
            #pragma unroll
            for (int r = 0; r < 5; ++r) {
                f32x4 a0 = a4[r*64 + k8*2], a1 = a4[r*64 + k8*2 + 1];
                accA[r] += dot4v(wa0, a0) + dot4v(wa1, a1);
                accB[r] += dot4v(wb0, a0) + dot4v(wb1, a1);
            }
        }
        #pragma unroll
        for (int r = 0; r < 5; ++r) {
            part_l[kq*320 + r*64 + 2*cp]     = accA[r];
            part_l[kq*320 + r*64 + 2*cp + 1] = accB[r];
        }
    }
    __syncthreads();
    if (tid < 320) {
        int r = tid >> 6, lc = tid & 63;
        float s = gb[(size_t)i*DM + q*64 + lc];
        #pragma unroll
        for (int kq = 0; kq < 16; ++kq) s += part_l[kq*320 + tid];
        int row = b*5 + r;
        int np  = (i == 0) ? row : (r*16 + b);
        s_g[((size_t)i*NTOK + np)*DM + q*64 + lc] = 1.f + silu_f(s);
    }
}

// ---------------- fused elementwise: o = x * s[plane], nontemporal ----------
__global__ __launch_bounds__(256) void k_elem(
    const float* __restrict__ x1, const float* __restrict__ x2,
    const float* __restrict__ x3, const float* __restrict__ x4,
    const float* __restrict__ audio, const float* __restrict__ s_g,
    float* __restrict__ out) {
    int b = blockIdx.x;
    int t = threadIdx.x;

    if (b < 512) {
        const float* s = s_g + 3 * NTOK * DM;
        const f32x4* xv = (const f32x4*)x4;
        f32x4* ov = (f32x4*)out;
        const int total4 = 1003520 / 4;
        for (int v = b * 256 + t; v < total4; v += 512 * 256) {
            f32x4 x = __builtin_nontemporal_load(&xv[v]);
#pragma unroll
            for (int j = 0; j < 4; ++j) {
                int idx = v * 4 + j;
                x[j] *= s[idx / 49];
            }
            __builtin_nontemporal_store(x, &ov[v]);
        }
    } else if (b < 1024) {
        const float* s = s_g + 2 * NTOK * DM;
        const f32x4* xv = (const f32x4*)x3;
        f32x4* ov = (f32x4*)(out + 1003520);
        const int total4 = 4014080 / 4;
        for (int v = (b - 512) * 256 + t; v < total4; v += 512 * 256) {
            float f = s[v / 49];
            f32x4 x = __builtin_nontemporal_load(&xv[v]);
            x *= f;
            __builtin_nontemporal_store(x, &ov[v]);
        }
    } else if (b < 2048) {
        const float* s = s_g + 1 * NTOK * DM;
        const f32x4* xv = (const f32x4*)x2;
        f32x4* ov = (f32x4*)(out + 5017600);
        const int total4 = 16056320 / 4;
        for (int v = (b - 1024) * 256 + t; v < total4; v += 1024 * 256) {
            float f = s[v / 196];
            f32x4 x = __builtin_nontemporal_load(&xv[v]);
            x *= f;
            __builtin_nontemporal_store(x, &ov[v]);
        }
    } else if (b < 6144) {
        const float* s = s_g;
        const f32x4* xv = (const f32x4*)x1;
        f32x4* ov = (f32x4*)(out + 21073920);
        const int total4 = 64225280 / 4;
        for (int v = (b - 2048) * 256 + t; v < total4; v += 4096 * 256) {
            float f = s[v / 784];
            f32x4 x = __builtin_nontemporal_load(&xv[v]);
            x *= f;
            __builtin_nontemporal_store(x, &ov[v]);
        }
    } else {
        int idx = (b - 6144) * 256 + t;
        out[85299200 + idx] = audio[idx];
    }
}

extern "C" void kernel_launch(void* const* d_in, const int* in_sizes, int n_in,
                              void* d_out, int out_size, void* d_ws, size_t ws_size,
                              hipStream_t stream) {
    const float* x1        = (const float*)d_in[0];
    const float* x2        = (const float*)d_in[1];
    const float* x3        = (const float*)d_in[2];
    const float* x4        = (const float*)d_in[3];
    const float* audio     = (const float*)d_in[4];
    const float* ln_g      = (const float*)d_in[5];
    const float* ln_b      = (const float*)d_in[6];
    const float* in_proj_w = (const float*)d_in[7];
    const float* conv_w    = (const float*)d_in[8];
    const float* conv_b    = (const float*)d_in[9];
    const float* xproj_w   = (const float*)d_in[10];
    const float* dt_w      = (const float*)d_in[11];
    const float* dt_b      = (const float*)d_in[12];
    const float* A_log     = (const float*)d_in[13];
    const float* Dvec      = (const float*)d_in[14];
    const float* out_proj_w= (const float*)d_in[15];
    const float* gate_w    = (const float*)d_in[16];
    const float* gate_b    = (const float*)d_in[17];

    float* ws = (float*)d_ws;

    k_tr<<<704, 256, 0, stream>>>(in_proj_w, out_proj_w, xproj_w, gate_w, ws);
    k_chain4b<<<256, 512, 0, stream>>>(audio, ln_g, ln_b, conv_w, conv_b,
                                       dt_w, dt_b, A_log, Dvec, gate_b, ws);
    k_elem<<<6224, 256, 0, stream>>>(x1, x2, x3, x4, audio, ws + OFF_SG,
                                     (float*)d_out);
}